// Round 4
// baseline (2911.516 us; speedup 1.0000x reference)
//
#include <hip/hip_runtime.h>

#define BB  64
#define TT  2048
#define HH  256
#define INW 64
#define BPG 16    // batches per workgroup

using bf16x8 = __attribute__((ext_vector_type(8))) short;
using f32x4  = __attribute__((ext_vector_type(4))) float;

__device__ __forceinline__ unsigned short f2bf(float x) {
    unsigned int u = __float_as_uint(x);
    return (unsigned short)((u + 0x7FFFu + ((u >> 16) & 1u)) >> 16);   // RTNE
}
__device__ __forceinline__ unsigned int packbf(float a, float b) {
    return (unsigned int)f2bf(a) | ((unsigned int)f2bf(b) << 16);
}
__device__ __forceinline__ float fast_tanh(float x) {
    float e = __expf(2.0f * x);
    return 1.0f - 2.0f / (e + 1.0f);
}
// Workgroup barrier WITHOUT vmcnt(0) drain: only LDS ops must land.
__device__ __forceinline__ void barrier_lds() {
    asm volatile("s_waitcnt lgkmcnt(0)\n\ts_barrier" ::: "memory");
}

// 4 WGs x 256 threads; WG g owns batches [16g,16g+16).
// D[m=h][n=batch] = W[h][k] @ r[batch][k]^T via mfma_f32_16x16x32_bf16.
// A-frags (weights, bf16) permanent in registers; B-frags (r, I) in LDS in
// fragment order: frag addr = kk*1024B + lane*16B (conflict-free contiguous),
// with a parity XOR-swizzle on the n index so writeback is 2-way (free).
// r double-buffered (1 raw barrier/step); I in 4 row-slots, prefetched
// 2 rows every even step with 2 steps of global-load slack.
__global__ __launch_bounds__(256, 1)
void rnn_scan_mfma(const float* __restrict__ x0,
                   const float* __restrict__ I,
                   const float* __restrict__ W_in,
                   const float* __restrict__ W_rec,
                   const float* __restrict__ bias,
                   float* __restrict__ u_out)
{
    __shared__ __align__(16) unsigned short r_lds[2][8][512];   // [buf][k-tile][frag]  16 KB
    __shared__ __align__(16) unsigned short i_lds[4][2][512];   // [row%4][k-tile][frag] 8 KB

    const int g    = blockIdx.x;
    const int tid  = threadIdx.x;
    const int w    = tid >> 6;
    const int lane = tid & 63;
    const int c    = lane & 15;
    const int q    = lane >> 4;
    const int h0   = w * 64;

    // swizzled lane slot for B-frag reads: n index XORed with 4*(q&1)
    const int lanep = lane ^ ((q & 1) << 2);

    // ---- A-frag weights: lane holds A[m=c][k=8q+j] of m-tile tau ----
    bf16x8 Arec[4][8], Ain[4][2];
    #pragma unroll
    for (int tau = 0; tau < 4; ++tau) {
        const float* wr = W_rec + (size_t)(h0 + tau * 16 + c) * HH + q * 8;
        #pragma unroll
        for (int kk = 0; kk < 8; ++kk) {
            bf16x8 f;
            #pragma unroll
            for (int j = 0; j < 8; ++j) f[j] = (short)f2bf(wr[kk * 32 + j]);
            Arec[tau][kk] = f;
        }
        const float* wi = W_in + (size_t)(h0 + tau * 16 + c) * INW + q * 8;
        #pragma unroll
        for (int kk = 0; kk < 2; ++kk) {
            bf16x8 f;
            #pragma unroll
            for (int j = 0; j < 8; ++j) f[j] = (short)f2bf(wi[kk * 32 + j]);
            Ain[tau][kk] = f;
        }
    }

    // bias as MFMA C-init; u state: u[tau][r] = u[batch=c][h0+tau*16+4q+r]
    f32x4 bvv[4], u[4];
    #pragma unroll
    for (int tau = 0; tau < 4; ++tau)
        bvv[tau] = *(const f32x4*)(bias + h0 + tau * 16 + 4 * q);
    {
        const float* x0p = x0 + (size_t)(g * BPG + c) * HH + h0 + 4 * q;
        #pragma unroll
        for (int tau = 0; tau < 4; ++tau) u[tau] = *(const f32x4*)(x0p + tau * 16);
    }

    // r writeback offsets (ushorts), loop-invariant
    int woff[4];
    #pragma unroll
    for (int tau = 0; tau < 4; ++tau) {
        const int kk_t = 2 * w + (tau >> 1);
        const int q_t  = (2 * tau + (q >> 1)) & 3;
        woff[tau] = kk_t * 512 + (q_t * 16 + (c ^ ((q_t & 1) << 2))) * 8 + ((q & 1) << 2);
    }

    // I staging geometry: thread -> (batch ib, k-span ij..ij+3)
    const int ib = tid >> 4;
    const int ij = (tid & 15) << 2;
    const int kk_i = ij >> 5, q_i = (ij >> 3) & 3, j0 = ij & 7;
    const int ioff = kk_i * 512 + (q_i * 16 + (ib ^ ((q_i & 1) << 2))) * 8 + j0;
    const float* Ib = I + (size_t)(g * BPG + ib) * TT * INW + ij;

    auto commit_i = [&](int slot, float4 v) {
        uint2 pk; pk.x = packbf(v.x, v.y); pk.y = packbf(v.z, v.w);
        *(uint2*)((unsigned short*)i_lds + slot * 1024 + ioff) = pk;
    };

    // ---- prologue: r_0 -> buf0, I rows 0,1 -> slots 0,1, rows 2,3 -> regs ----
    {
        unsigned short* rb = (unsigned short*)r_lds;
        #pragma unroll
        for (int tau = 0; tau < 4; ++tau) {
            uint2 pk;
            pk.x = packbf(fast_tanh(u[tau][0]), fast_tanh(u[tau][1]));
            pk.y = packbf(fast_tanh(u[tau][2]), fast_tanh(u[tau][3]));
            *(uint2*)(rb + woff[tau]) = pk;
        }
    }
    commit_i(0, *(const float4*)(Ib + (size_t)0 * INW));
    commit_i(1, *(const float4*)(Ib + (size_t)1 * INW));
    float4 pP0 = *(const float4*)(Ib + (size_t)2 * INW);
    float4 pP1 = *(const float4*)(Ib + (size_t)3 * INW);
    __syncthreads();

    float* uoutp = u_out + (size_t)(g * BPG + c) * TT * HH + h0 + 4 * q;

    auto mfma_step = [&](int rbuf, int islot, f32x4* acc) {
        const unsigned short* rb = (const unsigned short*)r_lds + rbuf * 4096;
        #pragma unroll
        for (int kk = 0; kk < 8; ++kk) {
            bf16x8 bf = *(const bf16x8*)(rb + kk * 512 + lanep * 8);
            #pragma unroll
            for (int tau = 0; tau < 4; ++tau)
                acc[tau] = __builtin_amdgcn_mfma_f32_16x16x32_bf16(Arec[tau][kk], bf, acc[tau], 0, 0, 0);
        }
        const unsigned short* ip = (const unsigned short*)i_lds + islot * 1024;
        #pragma unroll
        for (int kk = 0; kk < 2; ++kk) {
            bf16x8 bf = *(const bf16x8*)(ip + kk * 512 + lanep * 8);
            #pragma unroll
            for (int tau = 0; tau < 4; ++tau)
                acc[tau] = __builtin_amdgcn_mfma_f32_16x16x32_bf16(Ain[tau][kk], bf, acc[tau], 0, 0, 0);
        }
    };

    auto epilogue = [&](int t, int wbuf, const f32x4* acc) {
        unsigned short* rb = (unsigned short*)r_lds + wbuf * 4096;
        #pragma unroll
        for (int tau = 0; tau < 4; ++tau) {
            u[tau] = 0.8f * u[tau] + 0.2f * acc[tau];
            *(float4*)(uoutp + (size_t)t * HH + tau * 16) = *(const float4*)&u[tau];
            uint2 pk;
            pk.x = packbf(fast_tanh(u[tau][0]), fast_tanh(u[tau][1]));
            pk.y = packbf(fast_tanh(u[tau][2]), fast_tanh(u[tau][3]));
            *(uint2*)(rb + woff[tau]) = pk;
        }
    };

    for (int t0 = 0; t0 < TT; t0 += 2) {
        {   // even step t0: I traffic lives here
            commit_i((t0 + 2) & 3, pP0);             // rows t0+2, t0+3 (loaded t0-2)
            commit_i((t0 + 3) & 3, pP1);
            const int ra = (t0 + 4 < TT) ? t0 + 4 : TT - 1;
            const int rb_ = (t0 + 5 < TT) ? t0 + 5 : TT - 1;
            pP0 = *(const float4*)(Ib + (size_t)ra * INW);
            pP1 = *(const float4*)(Ib + (size_t)rb_ * INW);

            f32x4 acc[4] = {bvv[0], bvv[1], bvv[2], bvv[3]};
            mfma_step(0, t0 & 3, acc);
            epilogue(t0, 1, acc);
            barrier_lds();
        }
        {   // odd step t0+1
            f32x4 acc[4] = {bvv[0], bvv[1], bvv[2], bvv[3]};
            mfma_step(1, (t0 + 1) & 3, acc);
            epilogue(t0 + 1, 0, acc);
            barrier_lds();
        }
    }
}

// y[b,t,o] = sum_h u[b,t,h] * Wout[o,h] + bout[o]. One wave per (b,t) row.
__global__ __launch_bounds__(256)
void readout(const float* __restrict__ u,
             const float* __restrict__ Wout,
             const float* __restrict__ bout,
             float* __restrict__ y)
{
    const int wid  = threadIdx.x >> 6;
    const int lane = threadIdx.x & 63;
    const size_t row = (size_t)blockIdx.x * 4 + wid;

    float4 uv = ((const float4*)(u + row * HH))[lane];
    float4 w0 = ((const float4*)Wout)[lane];
    float4 w1 = ((const float4*)(Wout + HH))[lane];

    float acc0 = uv.x * w0.x + uv.y * w0.y + uv.z * w0.z + uv.w * w0.w;
    float acc1 = uv.x * w1.x + uv.y * w1.y + uv.z * w1.z + uv.w * w1.w;

    #pragma unroll
    for (int m = 32; m >= 1; m >>= 1) {
        acc0 += __shfl_xor(acc0, m, 64);
        acc1 += __shfl_xor(acc1, m, 64);
    }
    if (lane == 0) {
        y[row * 2 + 0] = acc0 + bout[0];
        y[row * 2 + 1] = acc1 + bout[1];
    }
}

extern "C" void kernel_launch(void* const* d_in, const int* in_sizes, int n_in,
                              void* d_out, int out_size, void* d_ws, size_t ws_size,
                              hipStream_t stream) {
    const float* x0    = (const float*)d_in[0];
    const float* I     = (const float*)d_in[1];
    const float* W_in  = (const float*)d_in[2];
    const float* W_rec = (const float*)d_in[3];
    const float* bias  = (const float*)d_in[4];
    const float* Wout  = (const float*)d_in[5];
    const float* bout  = (const float*)d_in[6];

    float* u_out = (float*)d_out;
    float* y_out = u_out + (size_t)BB * TT * HH;

    rnn_scan_mfma<<<BB / BPG, 256, 0, stream>>>(x0, I, W_in, W_rec, bias, u_out);
    readout<<<(BB * TT) / 4, 256, 0, stream>>>(u_out, Wout, bout, y_out);
}

// Round 5
// 2774.059 us; speedup vs baseline: 1.0496x; 1.0496x over previous
//
#include <hip/hip_runtime.h>
#include <hip/hip_bf16.h>

#define BB  64
#define TT  2048
#define HH  256
#define INW 64
#define BPG 16    // batches per scan workgroup

using bf16x8 = __attribute__((ext_vector_type(8))) short;
using f32x4  = __attribute__((ext_vector_type(4))) float;

__device__ __forceinline__ unsigned short f2bf(float x) {   // RTNE (one-time weight quant)
    unsigned int u = __float_as_uint(x);
    return (unsigned short)((u + 0x7FFFu + ((u >> 16) & 1u)) >> 16);
}
// round-half-up bf16 pair pack: 5 VALU ops (ties are measure-zero on random data)
__device__ __forceinline__ unsigned int packrn(float a, float b) {
    return ((__float_as_uint(a) + 0x8000u) >> 16) |
           ((__float_as_uint(b) + 0x8000u) & 0xFFFF0000u);
}
// tanh via exp + v_rcp (no div sequence): mul, exp, add, rcp, fma = 5 ops
__device__ __forceinline__ float fast_tanh(float x) {
    float e = __expf(2.0f * x);
    return __builtin_fmaf(-2.0f, __builtin_amdgcn_rcpf(e + 1.0f), 1.0f);
}
// barrier WITHOUT vmcnt(0) drain: only LDS ops must land
__device__ __forceinline__ void barrier_lds() {
    asm volatile("s_waitcnt lgkmcnt(0)\n\ts_barrier" ::: "memory");
}

// ---------------------------------------------------------------------------
// Pre-GEMM: P[rix][h] = sum_k I[rix][k]*W_in[h][k] + bias[h], rix = b*TT+t.
// P is written INTO the u-output region (consumed by the scan before each
// location is overwritten by the same thread's u-store).
// Block: 64 rows x 256 h. A = W_in (m=h), B = I rows (n=row), K=64.
// ---------------------------------------------------------------------------
__global__ __launch_bounds__(256, 2)
void input_gemm(const float* __restrict__ I, const float* __restrict__ W_in,
                const float* __restrict__ bias, float* __restrict__ P)
{
    __shared__ __align__(16) unsigned short i_t[4][2][512];   // [rowgrp][kk][frag] 8 KB

    const int tid  = threadIdx.x;
    const int w    = tid >> 6;
    const int lane = tid & 63;
    const int c    = lane & 15;
    const int q    = lane >> 4;
    const int h0   = w * 64;
    const size_t R0 = (size_t)blockIdx.x * 64;

    // stage I-tile as bf16 B-frags: thread -> row = tid>>2, k-span (tid&3)*16
    {
        const int row = tid >> 2, kc = (tid & 3) * 16;
        const float* ip = I + (R0 + row) * INW + kc;
        float4 v0 = ((const float4*)ip)[0], v1 = ((const float4*)ip)[1];
        float4 v2 = ((const float4*)ip)[2], v3 = ((const float4*)ip)[3];
        const int rg = row >> 4, n = row & 15;
        // element (k,n) lives at ushort off kk*512 + ((k>>3)&3)*128 + n*8 + (k&7)
        unsigned short* dst = &i_t[rg][0][0] + (kc >> 5) * 512 + ((kc >> 3) & 3) * 128 + n * 8;
        uint4 a, b2;
        a.x  = packrn(v0.x, v0.y); a.y  = packrn(v0.z, v0.w);
        a.z  = packrn(v1.x, v1.y); a.w  = packrn(v1.z, v1.w);
        b2.x = packrn(v2.x, v2.y); b2.y = packrn(v2.z, v2.w);
        b2.z = packrn(v3.x, v3.y); b2.w = packrn(v3.z, v3.w);
        *(uint4*)dst         = a;       // k = kc..kc+7
        *(uint4*)(dst + 128) = b2;      // k = kc+8..kc+15
    }

    // A-frags: lane holds W_in[h0 + tau*16 + c][kk*32 + q*8 + j]
    bf16x8 Aw[4][2];
    #pragma unroll
    for (int tau = 0; tau < 4; ++tau) {
        const float* wi = W_in + (size_t)(h0 + tau * 16 + c) * INW + q * 8;
        #pragma unroll
        for (int kk = 0; kk < 2; ++kk) {
            bf16x8 f;
            #pragma unroll
            for (int j = 0; j < 8; ++j) f[j] = (short)f2bf(wi[kk * 32 + j]);
            Aw[tau][kk] = f;
        }
    }
    f32x4 bv[4];
    #pragma unroll
    for (int tau = 0; tau < 4; ++tau)
        bv[tau] = *(const f32x4*)(bias + h0 + tau * 16 + 4 * q);

    __syncthreads();

    #pragma unroll
    for (int rg = 0; rg < 4; ++rg) {
        bf16x8 b0 = *(const bf16x8*)(&i_t[rg][0][lane * 8]);
        bf16x8 b1 = *(const bf16x8*)(&i_t[rg][1][lane * 8]);
        #pragma unroll
        for (int tau = 0; tau < 4; ++tau) {
            f32x4 acc = __builtin_amdgcn_mfma_f32_16x16x32_bf16(Aw[tau][0], b0, bv[tau], 0, 0, 0);
            acc = __builtin_amdgcn_mfma_f32_16x16x32_bf16(Aw[tau][1], b1, acc, 0, 0, 0);
            *(f32x4*)(P + (R0 + rg * 16 + c) * HH + h0 + tau * 16 + 4 * q) = acc;
        }
    }
}

// ---------------------------------------------------------------------------
// Scan: 4 WGs x 256 threads; WG g owns batches [16g,16g+16).
// D[m=h][n=batch] = W_rec @ r^T, mfma 16x16x32 bf16; weights in registers,
// r double-buffered in LDS (clean linear frags), input drive prefetched
// from P (in u_out region) with one-full-body (~4-step) slack.
// ---------------------------------------------------------------------------
__global__ __launch_bounds__(256, 1)
void rnn_scan_mfma(const float* __restrict__ x0,
                   const float* __restrict__ W_rec,
                   float* __restrict__ uP)          // = P on entry, u on exit
{
    __shared__ __align__(16) unsigned short r_lds[2][4096];   // [buf][8 kk * 512] 16 KB

    const int g    = blockIdx.x;
    const int tid  = threadIdx.x;
    const int w    = tid >> 6;
    const int lane = tid & 63;
    const int c    = lane & 15;
    const int q    = lane >> 4;
    const int h0   = w * 64;

    // A-frag weights: lane holds W_rec[h0 + tau*16 + c][kk*32 + q*8 + j]
    bf16x8 Arec[4][8];
    #pragma unroll
    for (int tau = 0; tau < 4; ++tau) {
        const float* wr = W_rec + (size_t)(h0 + tau * 16 + c) * HH + q * 8;
        #pragma unroll
        for (int kk = 0; kk < 8; ++kk) {
            bf16x8 f;
            #pragma unroll
            for (int j = 0; j < 8; ++j) f[j] = (short)f2bf(wr[kk * 32 + j]);
            Arec[tau][kk] = f;
        }
    }

    // u state: u[tau][r] = u[batch=c][h0 + tau*16 + 4q + r]
    f32x4 u[4];
    {
        const float* x0p = x0 + (size_t)(g * BPG + c) * HH + h0 + 4 * q;
        #pragma unroll
        for (int tau = 0; tau < 4; ++tau) u[tau] = *(const f32x4*)(x0p + tau * 16);
    }

    // r writeback: element (k=h, n=batch) at ushort off
    //   (k>>5)*512 + ((k>>3)&3)*128 + n*8 + (k&7); k = h0+16tau+4q+{0..3}
    int woff[4];
    #pragma unroll
    for (int tau = 0; tau < 4; ++tau)
        woff[tau] = (2 * w + (tau >> 1)) * 512 + (((2 * tau) + (q >> 1)) & 3) * 128
                  + c * 8 + (q & 1) * 4;

    // r_0 -> buf 0
    #pragma unroll
    for (int tau = 0; tau < 4; ++tau) {
        uint2 pk;
        pk.x = packrn(fast_tanh(u[tau][0]), fast_tanh(u[tau][1]));
        pk.y = packrn(fast_tanh(u[tau][2]), fast_tanh(u[tau][3]));
        *(uint2*)(&r_lds[0][0] + woff[tau]) = pk;
    }

    // P-load / u-store base (same addresses, same thread: program order keeps it safe)
    float* up = uP + (size_t)(g * BPG + c) * TT * HH + h0 + 4 * q;

    // prologue: preload P rows 0..3
    f32x4 hb0[4], hb1[4], hb2[4], hb3[4];
    #pragma unroll
    for (int tau = 0; tau < 4; ++tau) {
        hb0[tau] = *(const f32x4*)(up + (size_t)0 * HH + tau * 16);
        hb1[tau] = *(const f32x4*)(up + (size_t)1 * HH + tau * 16);
        hb2[tau] = *(const f32x4*)(up + (size_t)2 * HH + tau * 16);
        hb3[tau] = *(const f32x4*)(up + (size_t)3 * HH + tau * 16);
    }
    __syncthreads();

    auto do_step = [&](int t, const f32x4* Cin) {
        const int rbuf = t & 1;
        const unsigned short* rb = &r_lds[rbuf][0];
        f32x4 acc[4];
        {
            bf16x8 bf = *(const bf16x8*)(rb + lane * 8);
            #pragma unroll
            for (int tau = 0; tau < 4; ++tau)
                acc[tau] = __builtin_amdgcn_mfma_f32_16x16x32_bf16(Arec[tau][0], bf, Cin[tau], 0, 0, 0);
        }
        #pragma unroll
        for (int kk = 1; kk < 8; ++kk) {
            bf16x8 bf = *(const bf16x8*)(rb + kk * 512 + lane * 8);
            #pragma unroll
            for (int tau = 0; tau < 4; ++tau)
                acc[tau] = __builtin_amdgcn_mfma_f32_16x16x32_bf16(Arec[tau][kk], bf, acc[tau], 0, 0, 0);
        }
        unsigned short* wb = &r_lds[rbuf ^ 1][0];
        #pragma unroll
        for (int tau = 0; tau < 4; ++tau) {
            u[tau] = 0.8f * u[tau] + 0.2f * acc[tau];
            uint2 pk;
            pk.x = packrn(fast_tanh(u[tau][0]), fast_tanh(u[tau][1]));
            pk.y = packrn(fast_tanh(u[tau][2]), fast_tanh(u[tau][3]));
            *(uint2*)(wb + woff[tau]) = pk;
        }
        barrier_lds();
        // u stores post-barrier: off the critical chain, drain during next step
        #pragma unroll
        for (int tau = 0; tau < 4; ++tau)
            *(f32x4*)(up + (size_t)t * HH + tau * 16) = *(const f32x4*)&u[tau];
    };

    for (int t0 = 0; t0 < TT; t0 += 4) {
        // prefetch P rows t0+4..t0+7 (full-body slack; last iter re-reads, unused)
        const size_t tl = (size_t)((t0 + 4 < TT) ? t0 + 4 : t0);
        f32x4 g0[4], g1[4], g2[4], g3[4];
        #pragma unroll
        for (int tau = 0; tau < 4; ++tau) {
            g0[tau] = *(const f32x4*)(up + (tl + 0) * HH + tau * 16);
            g1[tau] = *(const f32x4*)(up + (tl + 1) * HH + tau * 16);
            g2[tau] = *(const f32x4*)(up + (tl + 2) * HH + tau * 16);
            g3[tau] = *(const f32x4*)(up + (tl + 3) * HH + tau * 16);
        }
        do_step(t0 + 0, hb0);
        do_step(t0 + 1, hb1);
        do_step(t0 + 2, hb2);
        do_step(t0 + 3, hb3);
        #pragma unroll
        for (int tau = 0; tau < 4; ++tau) {
            hb0[tau] = g0[tau]; hb1[tau] = g1[tau];
            hb2[tau] = g2[tau]; hb3[tau] = g3[tau];
        }
    }
}

// y[b,t,o] = sum_h u[b,t,h] * Wout[o,h] + bout[o]. One wave per (b,t) row.
__global__ __launch_bounds__(256)
void readout(const float* __restrict__ u,
             const float* __restrict__ Wout,
             const float* __restrict__ bout,
             float* __restrict__ y)
{
    const int wid  = threadIdx.x >> 6;
    const int lane = threadIdx.x & 63;
    const size_t row = (size_t)blockIdx.x * 4 + wid;

    float4 uv = ((const float4*)(u + row * HH))[lane];
    float4 w0 = ((const float4*)Wout)[lane];
    float4 w1 = ((const float4*)(Wout + HH))[lane];

    float acc0 = uv.x * w0.x + uv.y * w0.y + uv.z * w0.z + uv.w * w0.w;
    float acc1 = uv.x * w1.x + uv.y * w1.y + uv.z * w1.z + uv.w * w1.w;

    #pragma unroll
    for (int m = 32; m >= 1; m >>= 1) {
        acc0 += __shfl_xor(acc0, m, 64);
        acc1 += __shfl_xor(acc1, m, 64);
    }
    if (lane == 0) {
        y[row * 2 + 0] = acc0 + bout[0];
        y[row * 2 + 1] = acc1 + bout[1];
    }
}

extern "C" void kernel_launch(void* const* d_in, const int* in_sizes, int n_in,
                              void* d_out, int out_size, void* d_ws, size_t ws_size,
                              hipStream_t stream) {
    const float* x0    = (const float*)d_in[0];
    const float* I     = (const float*)d_in[1];
    const float* W_in  = (const float*)d_in[2];
    const float* W_rec = (const float*)d_in[3];
    const float* bias  = (const float*)d_in[4];
    const float* Wout  = (const float*)d_in[5];
    const float* bout  = (const float*)d_in[6];

    float* u_out = (float*)d_out;                       // doubles as P scratch
    float* y_out = u_out + (size_t)BB * TT * HH;

    input_gemm<<<(BB * TT) / 64, 256, 0, stream>>>(I, W_in, bias, u_out);
    rnn_scan_mfma<<<BB / BPG, 256, 0, stream>>>(x0, W_rec, u_out);
    readout<<<(BB * TT) / 4, 256, 0, stream>>>(u_out, Wout, bout, y_out);
}